// Round 18
// baseline (46.049 us; speedup 1.0000x reference)
//
#include <hip/hip_runtime.h>

#define NF 512
#define MB 2048
#define PL (NF * NF)  // bf16 elements per 512x512 plane
#define LDT 72

typedef __attribute__((ext_vector_type(8))) short bf16x8;
typedef __attribute__((ext_vector_type(4))) float f32x4;
typedef __attribute__((ext_vector_type(4))) int i32x4;

__device__ __forceinline__ float2 cmul(float2 a, float2 b) {
  return make_float2(fmaf(a.x, b.x, -(a.y * b.y)), fmaf(a.x, b.y, a.y * b.x));
}
__device__ __forceinline__ float2 cfma(float2 a, float2 b, float2 c) {
  return make_float2(fmaf(a.x, b.x, fmaf(-a.y, b.y, c.x)),
                     fmaf(a.x, b.y, fmaf(a.y, b.x, c.y)));
}
__device__ __forceinline__ unsigned short f2bf(float f) {
  union { float f; unsigned u; } v; v.f = f;
  unsigned r = v.u + 0x7FFF + ((v.u >> 16) & 1);
  return (unsigned short)(r >> 16);
}

// ---------------- angle -> MZI coefficient set (R17-proven) ----------------
__device__ __forceinline__ void mzi_coef(float ang0, float ang1,
                                         float4& k0, float4& k1)
{
  float se, ce, st, ct;
  __sincosf(ang0, &se, &ce);
  __sincosf(ang1, &st, &ct);
  float2 ephi = make_float2(ce, se);
  float2 tt = make_float2(0.5f * (ct - 1.0f), 0.5f * st);
  float2 uu = make_float2(0.5f * (ct + 1.0f), 0.5f * st);
  float2 C1 = cmul(ephi, tt);
  float2 C2 = make_float2(-uu.y, uu.x);
  float2 eu = cmul(ephi, uu);
  float2 C3 = make_float2(-eu.y, eu.x);
  float2 C4 = make_float2(-tt.x, -tt.y);
  k0 = make_float4(C1.x, C1.y, C2.x, C2.y);
  k1 = make_float4(C3.x, C3.y, C4.x, C4.y);
}

// ---------------- K2: 2 chunks x 32 steps, 1 col/wave, angle-direct (R17-proven) ----------------
struct MZS { float2 a0, b0, a1, b1; };
struct Angs { float a00, a01, a10, a11, b00, b01, b10, b11; };

__device__ __forceinline__ void mzi_apply(const float4& k0, const float4& k1,
                                          float2& a, float2& b) {
  float2 c1 = make_float2(k0.x, k0.y), c2 = make_float2(k0.z, k0.w);
  float2 c3 = make_float2(k1.x, k1.y), c4 = make_float2(k1.z, k1.w);
  float2 na = cfma(c2, b, cmul(c1, a));
  float2 nb = cfma(c4, b, cmul(c3, a));
  a = na; b = nb;
}
__device__ __forceinline__ float2 mzi_bnd(const float4& k0, const float4& k1,
                                          float2& a, float2 b, bool en) {
  float2 d1 = make_float2(k0.x, k0.y), d2 = make_float2(k0.z, k0.w);
  float2 d3 = make_float2(k1.x, k1.y), d4 = make_float2(k1.z, k1.w);
  float2 na = cfma(d2, b, cmul(d1, a));
  float2 nb = cfma(d4, b, cmul(d3, a));
  if (en) a = na;
  return en ? nb : make_float2(0.f, 0.f);
}

__device__ __forceinline__ void load_angs(Angs& G,
    const float* __restrict__ a0, const float* __restrict__ a1,
    const float* __restrict__ b0, const float* __restrict__ b1,
    int l, int q0, int q1, int bq1)
{
  G.a00 = a0[l * 256 + q0];  G.a01 = a0[l * 256 + q1];
  G.a10 = a1[l * 256 + q0];  G.a11 = a1[l * 256 + q1];
  G.b00 = b0[l * 255 + q0];  G.b01 = b0[l * 255 + bq1];
  G.b10 = b1[l * 255 + q0];  G.b11 = b1[l * 255 + bq1];
}

__device__ __forceinline__ void step_angs(const Angs& G, int L, bool hasBnd, MZS& s)
{
  float4 K0, K1, K2, K3, K4, K5, K6, K7;
  mzi_coef(G.a00, G.a10, K0, K1);
  mzi_coef(G.a01, G.a11, K2, K3);
  mzi_coef(G.b00, G.b10, K4, K5);
  mzi_coef(G.b01, G.b11, K6, K7);
  mzi_apply(K0, K1, s.a0, s.b0);
  mzi_apply(K2, K3, s.a1, s.b1);
  float xnx = __shfl_down(s.a0.x, 1);
  float xny = __shfl_down(s.a0.y, 1);
  float2 xn = (L == 63) ? make_float2(0.f, 0.f) : make_float2(xnx, xny);
  float2 nbo = mzi_bnd(K6, K7, s.b1, xn, hasBnd);
  mzi_apply(K4, K5, s.b0, s.a1);
  float px = __shfl_up(nbo.x, 1);
  float py = __shfl_up(nbo.y, 1);
  if (L > 0) s.a0 = make_float2(px, py);
}

__global__ __launch_bounds__(64) void chunk_mesh(
    const float* __restrict__ a0, const float* __restrict__ a1,
    const float* __restrict__ b0, const float* __restrict__ b1,
    unsigned short* __restrict__ Cb)     // C0 TRANSPOSED plane, C1 NORMAL plane
{
  const int bid = blockIdx.x;                  // 0..1023
  const int m = bid >> 9;
  const int cb = bid & 511;
  const int j = (cb & 7) * 64 + (cb >> 3);
  const int L = threadIdx.x;
  const int p0 = j >> 1;
  int ws = p0 - 63; ws = ws < 0 ? 0 : (ws > 128 ? 128 : ws);
  const int q0 = ws + 2 * L, q1 = q0 + 1;
  const bool hasBnd = (q1 < 255);
  const int bq1 = hasBnd ? q1 : 254;

  MZS s;
  s.a0 = make_float2((2 * q0     == j) ? 1.f : 0.f, 0.f);
  s.b0 = make_float2((2 * q0 + 1 == j) ? 1.f : 0.f, 0.f);
  s.a1 = make_float2((2 * q1     == j) ? 1.f : 0.f, 0.f);
  s.b1 = make_float2((2 * q1 + 1 == j) ? 1.f : 0.f, 0.f);

  const int l0 = m * 32;
  Angs G0, G1;
  load_angs(G0, a0, a1, b0, b1, l0 + 0, q0, q1, bq1);
  load_angs(G1, a0, a1, b0, b1, l0 + 1, q0, q1, bq1);

#pragma unroll 1
  for (int i = 0; i < 30; i += 2) {
    step_angs(G0, L, hasBnd, s);
    load_angs(G0, a0, a1, b0, b1, l0 + i + 2, q0, q1, bq1);
    step_angs(G1, L, hasBnd, s);
    load_angs(G1, a0, a1, b0, b1, l0 + ((i + 3 < 32) ? i + 3 : 31), q0, q1, bq1);
  }
  step_angs(G0, L, hasBnd, s);
  step_angs(G1, L, hasBnd, s);

  unsigned short* Cr = Cb + (size_t)m * 2 * PL;
  unsigned short* Ci = Cr + PL;
  if (m == 0) {
    const int col0 = 2 * q0;
    ushort4 vr, vi;
    vr.x = f2bf(s.a0.x); vr.y = f2bf(s.b0.x); vr.z = f2bf(s.a1.x); vr.w = f2bf(s.b1.x);
    vi.x = f2bf(s.a0.y); vi.y = f2bf(s.b0.y); vi.z = f2bf(s.a1.y); vi.w = f2bf(s.b1.y);
    *(ushort4*)&Cr[(size_t)j * NF + col0] = vr;
    *(ushort4*)&Ci[(size_t)j * NF + col0] = vi;
    const int z0 = (col0 + 256) & 511;
    const int z1 = (col0 + 258) & 511;
    const ushort2 zz = make_ushort2(0, 0);
    *(ushort2*)&Cr[(size_t)j * NF + z0] = zz;
    *(ushort2*)&Cr[(size_t)j * NF + z1] = zz;
    *(ushort2*)&Ci[(size_t)j * NF + z0] = zz;
    *(ushort2*)&Ci[(size_t)j * NF + z1] = zz;
  } else {
    const int rows[4] = {2 * q0, 2 * q0 + 1, 2 * q1, 2 * q1 + 1};
    const float2 vals[4] = {s.a0, s.b0, s.a1, s.b1};
#pragma unroll
    for (int e = 0; e < 4; ++e) {
      Cr[(size_t)rows[e] * NF + j] = f2bf(vals[e].x);
      Ci[(size_t)rows[e] * NF + j] = f2bf(vals[e].y);
    }
#pragma unroll
    for (int e = 0; e < 4; ++e) {
      const int row = (2 * ws + 256 + 4 * L + e) & 511;
      Cr[(size_t)row * NF + j] = 0;
      Ci[(size_t)row * NF + j] = 0;
    }
  }
}

// ---------------- K3: U = C1 * C0 — BN=32 retile, 256 blocks (1/CU) ----------------
// out[i][j] = sum_k C1[i][k] * C0T[j][k]
__global__ __launch_bounds__(256) void prodU_kernel(
    const unsigned short* __restrict__ Cb, unsigned short* __restrict__ Up)
{
  __shared__ __align__(16) unsigned short Ars[32][LDT];
  __shared__ __align__(16) unsigned short Ais[32][LDT];
  __shared__ __align__(16) unsigned short Brs[32][LDT];
  __shared__ __align__(16) unsigned short Bis[32][LDT];

  const int tid = threadIdx.x;
  const int w = tid >> 6, wm = w & 1, wn = w >> 1, lane = tid & 63;
  const int t = blockIdx.x;                    // 0..255
  const int bm = (t >> 4) * 32, bn = (t & 15) * 32;
  const unsigned short* Agr = Cb + (size_t)2 * PL;     // C1 N-plane (A-slot)
  const unsigned short* Agi = Agr + PL;
  const unsigned short* Bgr = Cb;                      // C0 T-plane (B-slot)
  const unsigned short* Bgi = Bgr + PL;
  unsigned short* Or = Up;
  unsigned short* Oi = Up + PL;

  const int hw = 70;
  int klo = bm - hw; { int u = bn - hw; if (u > klo) klo = u; }
  if (klo < 0) klo = 0; klo &= ~63;
  int khi = bm + 32 + hw; { int u = bn + 32 + hw; if (u < khi) khi = u; }
  if (khi > NF) khi = NF; khi = (khi + 63) & ~63;

  f32x4 acc_r = (f32x4){0.f, 0.f, 0.f, 0.f};
  f32x4 acc_i = (f32x4){0.f, 0.f, 0.f, 0.f};
  const int sr = tid >> 3, sk = (tid & 7) * 8;

  for (int k0 = klo; k0 < khi; k0 += 64) {
    uint4 ar = *(const uint4*)(Agr + (size_t)(bm + sr) * NF + k0 + sk);
    uint4 ai = *(const uint4*)(Agi + (size_t)(bm + sr) * NF + k0 + sk);
    uint4 br = *(const uint4*)(Bgr + (size_t)(bn + sr) * NF + k0 + sk);
    uint4 bi = *(const uint4*)(Bgi + (size_t)(bn + sr) * NF + k0 + sk);

    __syncthreads();

    *(uint4*)&Ars[sr][sk] = ar;
    *(uint4*)&Ais[sr][sk] = ai;
    *(uint4*)&Brs[sr][sk] = br;
    *(uint4*)&Bis[sr][sk] = bi;

    __syncthreads();

#pragma unroll
    for (int kk = 0; kk < 2; ++kk) {
      const int ko = kk * 32 + (lane >> 4) * 8;
      bf16x8 afr = *(const bf16x8*)&Ars[wm * 16 + (lane & 15)][ko];
      bf16x8 afi = *(const bf16x8*)&Ais[wm * 16 + (lane & 15)][ko];
      i32x4 neg = (i32x4)afi ^ (int)0x80008000;
      bf16x8 afin = (bf16x8)neg;
      bf16x8 bfr = *(const bf16x8*)&Brs[wn * 16 + (lane & 15)][ko];
      bf16x8 bfi = *(const bf16x8*)&Bis[wn * 16 + (lane & 15)][ko];
      acc_r = __builtin_amdgcn_mfma_f32_16x16x32_bf16(afr,  bfr, acc_r, 0, 0, 0);
      acc_r = __builtin_amdgcn_mfma_f32_16x16x32_bf16(afin, bfi, acc_r, 0, 0, 0);
      acc_i = __builtin_amdgcn_mfma_f32_16x16x32_bf16(afr,  bfi, acc_i, 0, 0, 0);
      acc_i = __builtin_amdgcn_mfma_f32_16x16x32_bf16(afi,  bfr, acc_i, 0, 0, 0);
    }
  }

  const int dn0 = bn + wn * 16 + (lane & 15);
  const int dm0 = bm + wm * 16 + (lane >> 4) * 4;
#pragma unroll
  for (int r = 0; r < 4; ++r) {
    Or[(size_t)(dm0 + r) * NF + dn0] = f2bf(acc_r[r]);
    Oi[(size_t)(dm0 + r) * NF + dn0] = f2bf(acc_i[r]);
  }
}

// ---------------- K4: final banded GEMM — BN=32 retile, 1024 blocks (4/CU) ----------------
__global__ __launch_bounds__(256) void gemm_kernel(
    const float2* __restrict__ Xf,
    const unsigned short* __restrict__ Ur, const unsigned short* __restrict__ Ui,
    const float* __restrict__ omega, float2* __restrict__ Y)
{
  __shared__ __align__(16) unsigned short Ars[32][LDT];
  __shared__ __align__(16) unsigned short Ais[32][LDT];
  __shared__ __align__(16) unsigned short Brs[32][LDT];
  __shared__ __align__(16) unsigned short Bis[32][LDT];

  const int tid = threadIdx.x;
  const int w = tid >> 6, wm = w & 1, wn = w >> 1, lane = tid & 63;
  const int bm = (int)(blockIdx.x >> 4) * 32;   // 64 m-tiles
  const int bn = (int)(blockIdx.x & 15) * 32;   // 16 n-tiles

  int klo = bn - 140; if (klo < 0) klo = 0; klo &= ~63;
  int khi = bn + 172; if (khi > NF) khi = NF; khi = (khi + 63) & ~63;

  f32x4 acc_r = (f32x4){0.f, 0.f, 0.f, 0.f};
  f32x4 acc_i = (f32x4){0.f, 0.f, 0.f, 0.f};
  const int sr = tid >> 3, sk = (tid & 7) * 8;

  for (int k0 = klo; k0 < khi; k0 += 64) {
    ushort4 ar2[2], ai2[2];
    const float4* xs = (const float4*)(Xf + (size_t)(bm + sr) * NF + k0 + sk);
#pragma unroll
    for (int h = 0; h < 2; ++h) {
      float4 v0 = xs[2 * h], v1 = xs[2 * h + 1];
      ar2[h].x = f2bf(v0.x); ai2[h].x = f2bf(v0.y);
      ar2[h].y = f2bf(v0.z); ai2[h].y = f2bf(v0.w);
      ar2[h].z = f2bf(v1.x); ai2[h].z = f2bf(v1.y);
      ar2[h].w = f2bf(v1.z); ai2[h].w = f2bf(v1.w);
    }
    uint4 br = *(const uint4*)(Ur + (size_t)(bn + sr) * NF + k0 + sk);
    uint4 bi = *(const uint4*)(Ui + (size_t)(bn + sr) * NF + k0 + sk);

    if (k0 > klo) __syncthreads();

    *(ushort4*)&Ars[sr][sk]     = ar2[0];
    *(ushort4*)&Ars[sr][sk + 4] = ar2[1];
    *(ushort4*)&Ais[sr][sk]     = ai2[0];
    *(ushort4*)&Ais[sr][sk + 4] = ai2[1];
    *(uint4*)&Brs[sr][sk]       = br;
    *(uint4*)&Bis[sr][sk]       = bi;

    __syncthreads();

#pragma unroll
    for (int kk = 0; kk < 2; ++kk) {
      const int ko = kk * 32 + (lane >> 4) * 8;
      bf16x8 afr = *(const bf16x8*)&Ars[wm * 16 + (lane & 15)][ko];
      bf16x8 afi = *(const bf16x8*)&Ais[wm * 16 + (lane & 15)][ko];
      i32x4 neg = (i32x4)afi ^ (int)0x80008000;
      bf16x8 afin = (bf16x8)neg;
      bf16x8 bfr = *(const bf16x8*)&Brs[wn * 16 + (lane & 15)][ko];
      bf16x8 bfi = *(const bf16x8*)&Bis[wn * 16 + (lane & 15)][ko];
      acc_r = __builtin_amdgcn_mfma_f32_16x16x32_bf16(afr,  bfr, acc_r, 0, 0, 0);
      acc_r = __builtin_amdgcn_mfma_f32_16x16x32_bf16(afin, bfi, acc_r, 0, 0, 0);
      acc_i = __builtin_amdgcn_mfma_f32_16x16x32_bf16(afr,  bfi, acc_i, 0, 0, 0);
      acc_i = __builtin_amdgcn_mfma_f32_16x16x32_bf16(afi,  bfr, acc_i, 0, 0, 0);
    }
  }

  const int dn0 = bn + wn * 16 + (lane & 15);
  const int dm0 = bm + wm * 16 + (lane >> 4) * 4;
  float sn, cn;
  sincosf(omega[dn0], &sn, &cn);
#pragma unroll
  for (int r = 0; r < 4; ++r) {
    float yr = acc_r[r], yi = acc_i[r];
    Y[(size_t)(dm0 + r) * NF + dn0] =
        make_float2(fmaf(yr, cn, -(yi * sn)), fmaf(yr, sn, yi * cn));
  }
}

extern "C" void kernel_launch(void* const* d_in, const int* in_sizes, int n_in,
                              void* d_out, int out_size, void* d_ws, size_t ws_size,
                              hipStream_t stream) {
  const float2* Xf   = (const float2*)d_in[0];
  const float* a0    = (const float*)d_in[1];
  const float* a1    = (const float*)d_in[2];
  const float* b0    = (const float*)d_in[3];
  const float* b1    = (const float*)d_in[4];
  const float* omega = (const float*)d_in[5];

  size_t off = 0;
  unsigned short* Cb = (unsigned short*)((char*)d_ws + off); off += (size_t)2 * 2 * PL * 2;
  unsigned short* Up = (unsigned short*)((char*)d_ws + off); off += (size_t)1 * 2 * PL * 2;
  float2* Y = (float2*)d_out;

  chunk_mesh<<<1024, 64, 0, stream>>>(a0, a1, b0, b1, Cb);
  prodU_kernel<<<256, 256, 0, stream>>>(Cb, Up);
  gemm_kernel<<<(MB / 32) * (NF / 32), 256, 0, stream>>>(Xf, Up, Up + PL, omega, Y);
}

// Round 19
// 42.460 us; speedup vs baseline: 1.0845x; 1.0845x over previous
//
#include <hip/hip_runtime.h>

#define NF 512
#define MB 2048
#define PL (NF * NF)  // bf16 elements per 512x512 plane
#define LDT 72

typedef __attribute__((ext_vector_type(8))) short bf16x8;
typedef __attribute__((ext_vector_type(4))) float f32x4;
typedef __attribute__((ext_vector_type(4))) int i32x4;

__device__ __forceinline__ float2 cmul(float2 a, float2 b) {
  return make_float2(fmaf(a.x, b.x, -(a.y * b.y)), fmaf(a.x, b.y, a.y * b.x));
}
__device__ __forceinline__ float2 cfma(float2 a, float2 b, float2 c) {
  return make_float2(fmaf(a.x, b.x, fmaf(-a.y, b.y, c.x)),
                     fmaf(a.x, b.y, fmaf(a.y, b.x, c.y)));
}
__device__ __forceinline__ unsigned short f2bf(float f) {
  union { float f; unsigned u; } v; v.f = f;
  unsigned r = v.u + 0x7FFF + ((v.u >> 16) & 1);
  return (unsigned short)(r >> 16);
}

// ---------------- angle -> MZI coefficient set (R17-proven) ----------------
__device__ __forceinline__ void mzi_coef(float ang0, float ang1,
                                         float4& k0, float4& k1)
{
  float se, ce, st, ct;
  __sincosf(ang0, &se, &ce);     // ephi = (ce, se)
  __sincosf(ang1, &st, &ct);     // eth  = (ct, st)
  float2 ephi = make_float2(ce, se);
  float2 tt = make_float2(0.5f * (ct - 1.0f), 0.5f * st);
  float2 uu = make_float2(0.5f * (ct + 1.0f), 0.5f * st);
  float2 C1 = cmul(ephi, tt);
  float2 C2 = make_float2(-uu.y, uu.x);
  float2 eu = cmul(ephi, uu);
  float2 C3 = make_float2(-eu.y, eu.x);
  float2 C4 = make_float2(-tt.x, -tt.y);
  k0 = make_float4(C1.x, C1.y, C2.x, C2.y);
  k1 = make_float4(C3.x, C3.y, C4.x, C4.y);
}

// ---------------- K2: 2 chunks x 32 steps, 1 col/wave, angle-direct (R17-proven) ----------------
struct MZS { float2 a0, b0, a1, b1; };
struct Angs { float a00, a01, a10, a11, b00, b01, b10, b11; };

__device__ __forceinline__ void mzi_apply(const float4& k0, const float4& k1,
                                          float2& a, float2& b) {
  float2 c1 = make_float2(k0.x, k0.y), c2 = make_float2(k0.z, k0.w);
  float2 c3 = make_float2(k1.x, k1.y), c4 = make_float2(k1.z, k1.w);
  float2 na = cfma(c2, b, cmul(c1, a));
  float2 nb = cfma(c4, b, cmul(c3, a));
  a = na; b = nb;
}
__device__ __forceinline__ float2 mzi_bnd(const float4& k0, const float4& k1,
                                          float2& a, float2 b, bool en) {
  float2 d1 = make_float2(k0.x, k0.y), d2 = make_float2(k0.z, k0.w);
  float2 d3 = make_float2(k1.x, k1.y), d4 = make_float2(k1.z, k1.w);
  float2 na = cfma(d2, b, cmul(d1, a));
  float2 nb = cfma(d4, b, cmul(d3, a));
  if (en) a = na;
  return en ? nb : make_float2(0.f, 0.f);
}

__device__ __forceinline__ void load_angs(Angs& G,
    const float* __restrict__ a0, const float* __restrict__ a1,
    const float* __restrict__ b0, const float* __restrict__ b1,
    int l, int q0, int q1, int bq1)
{
  G.a00 = a0[l * 256 + q0];  G.a01 = a0[l * 256 + q1];
  G.a10 = a1[l * 256 + q0];  G.a11 = a1[l * 256 + q1];
  G.b00 = b0[l * 255 + q0];  G.b01 = b0[l * 255 + bq1];
  G.b10 = b1[l * 255 + q0];  G.b11 = b1[l * 255 + bq1];
}

__device__ __forceinline__ void step_angs(const Angs& G, int L, bool hasBnd, MZS& s)
{
  float4 K0, K1, K2, K3, K4, K5, K6, K7;
  mzi_coef(G.a00, G.a10, K0, K1);    // A @ q0
  mzi_coef(G.a01, G.a11, K2, K3);    // A @ q1
  mzi_coef(G.b00, G.b10, K4, K5);    // B @ q0 (always exists: q0 <= 254)
  mzi_coef(G.b01, G.b11, K6, K7);    // B @ q1 (discarded when !hasBnd)
  mzi_apply(K0, K1, s.a0, s.b0);
  mzi_apply(K2, K3, s.a1, s.b1);
  float xnx = __shfl_down(s.a0.x, 1);
  float xny = __shfl_down(s.a0.y, 1);
  float2 xn = (L == 63) ? make_float2(0.f, 0.f) : make_float2(xnx, xny);
  float2 nbo = mzi_bnd(K6, K7, s.b1, xn, hasBnd);
  mzi_apply(K4, K5, s.b0, s.a1);
  float px = __shfl_up(nbo.x, 1);
  float py = __shfl_up(nbo.y, 1);
  if (L > 0) s.a0 = make_float2(px, py);
}

__global__ __launch_bounds__(64) void chunk_mesh(
    const float* __restrict__ a0, const float* __restrict__ a1,
    const float* __restrict__ b0, const float* __restrict__ b1,
    unsigned short* __restrict__ Cb)     // C0 TRANSPOSED plane, C1 NORMAL plane
{
  const int bid = blockIdx.x;                  // 0..1023
  const int m = bid >> 9;                      // chunk (steps 32m..32m+31)
  const int cb = bid & 511;
  const int j = (cb & 7) * 64 + (cb >> 3);     // bijective XCD swizzle (512 = 8*64)
  const int L = threadIdx.x;
  const int p0 = j >> 1;
  int ws = p0 - 63; ws = ws < 0 ? 0 : (ws > 128 ? 128 : ws);
  const int q0 = ws + 2 * L, q1 = q0 + 1;
  const bool hasBnd = (q1 < 255);
  const int bq1 = hasBnd ? q1 : 254;           // clamped b-angle index (value unused when !hasBnd)

  MZS s;
  s.a0 = make_float2((2 * q0     == j) ? 1.f : 0.f, 0.f);
  s.b0 = make_float2((2 * q0 + 1 == j) ? 1.f : 0.f, 0.f);
  s.a1 = make_float2((2 * q1     == j) ? 1.f : 0.f, 0.f);
  s.b1 = make_float2((2 * q1 + 1 == j) ? 1.f : 0.f, 0.f);

  const int l0 = m * 32;
  Angs G0, G1;
  load_angs(G0, a0, a1, b0, b1, l0 + 0, q0, q1, bq1);
  load_angs(G1, a0, a1, b0, b1, l0 + 1, q0, q1, bq1);

#pragma unroll 1
  for (int i = 0; i < 30; i += 2) {
    step_angs(G0, L, hasBnd, s);
    load_angs(G0, a0, a1, b0, b1, l0 + i + 2, q0, q1, bq1);
    step_angs(G1, L, hasBnd, s);
    load_angs(G1, a0, a1, b0, b1, l0 + ((i + 3 < 32) ? i + 3 : 31), q0, q1, bq1);
  }
  step_angs(G0, L, hasBnd, s);                 // step 30
  step_angs(G1, L, hasBnd, s);                 // step 31

  unsigned short* Cr = Cb + (size_t)m * 2 * PL;
  unsigned short* Ci = Cr + PL;
  if (m == 0) {
    // TRANSPOSED plane [col][row]: row j holds column j of C0 (R15/R16/R17-proven write)
    const int col0 = 2 * q0;
    ushort4 vr, vi;
    vr.x = f2bf(s.a0.x); vr.y = f2bf(s.b0.x); vr.z = f2bf(s.a1.x); vr.w = f2bf(s.b1.x);
    vi.x = f2bf(s.a0.y); vi.y = f2bf(s.b0.y); vi.z = f2bf(s.a1.y); vi.w = f2bf(s.b1.y);
    *(ushort4*)&Cr[(size_t)j * NF + col0] = vr;
    *(ushort4*)&Ci[(size_t)j * NF + col0] = vi;
    const int z0 = (col0 + 256) & 511;
    const int z1 = (col0 + 258) & 511;
    const ushort2 zz = make_ushort2(0, 0);
    *(ushort2*)&Cr[(size_t)j * NF + z0] = zz;
    *(ushort2*)&Cr[(size_t)j * NF + z1] = zz;
    *(ushort2*)&Ci[(size_t)j * NF + z0] = zz;
    *(ushort2*)&Ci[(size_t)j * NF + z1] = zz;
  } else {
    // NORMAL plane [row][col] (R14/R16/R17-proven write)
    const int rows[4] = {2 * q0, 2 * q0 + 1, 2 * q1, 2 * q1 + 1};
    const float2 vals[4] = {s.a0, s.b0, s.a1, s.b1};
#pragma unroll
    for (int e = 0; e < 4; ++e) {
      Cr[(size_t)rows[e] * NF + j] = f2bf(vals[e].x);
      Ci[(size_t)rows[e] * NF + j] = f2bf(vals[e].y);
    }
#pragma unroll
    for (int e = 0; e < 4; ++e) {
      const int row = (2 * ws + 256 + 4 * L + e) & 511;
      Cr[(size_t)row * NF + j] = 0;
      Ci[(size_t)row * NF + j] = 0;
    }
  }
}

// ---------------- product tile (R12/R15/R16/R17-proven): D[a][b] = sum_k A[a][k]*B[b][k] ----------------
__device__ void prod_tile(
    const unsigned short* __restrict__ Agr, const unsigned short* __restrict__ Agi,
    const unsigned short* __restrict__ Bgr, const unsigned short* __restrict__ Bgi,
    unsigned short* __restrict__ Or, unsigned short* __restrict__ Oi,
    int bm, int bn, int klo, int khi, int tid,
    unsigned short (*Ars)[LDT], unsigned short (*Ais)[LDT],
    unsigned short (*Brs)[LDT], unsigned short (*Bis)[LDT])
{
  const int w = tid >> 6, wm = w & 1, wn = w >> 1, lane = tid & 63;
  f32x4 acc_r[2], acc_i[2];
#pragma unroll
  for (int nf = 0; nf < 2; ++nf) {
    acc_r[nf] = (f32x4){0.f, 0.f, 0.f, 0.f};
    acc_i[nf] = (f32x4){0.f, 0.f, 0.f, 0.f};
  }
  const int sar = tid >> 3, sak = (tid & 7) * 8;
  const int sbr = tid >> 2, sbk = (tid & 3) * 16;

  for (int k0 = klo; k0 < khi; k0 += 64) {
    const uint4* gar = (const uint4*)(Agr + (size_t)(bm + sar) * NF + k0 + sak);
    const uint4* gai = (const uint4*)(Agi + (size_t)(bm + sar) * NF + k0 + sak);
    const uint4* gbr = (const uint4*)(Bgr + (size_t)(bn + sbr) * NF + k0 + sbk);
    const uint4* gbi = (const uint4*)(Bgi + (size_t)(bn + sbr) * NF + k0 + sbk);
    uint4 ar = gar[0];
    uint4 ai = gai[0];
    uint4 br0 = gbr[0], br1 = gbr[1];
    uint4 bi0 = gbi[0], bi1 = gbi[1];

    __syncthreads();

    *(uint4*)&Ars[sar][sak]     = ar;
    *(uint4*)&Ais[sar][sak]     = ai;
    *(uint4*)&Brs[sbr][sbk]     = br0;
    *(uint4*)&Brs[sbr][sbk + 8] = br1;
    *(uint4*)&Bis[sbr][sbk]     = bi0;
    *(uint4*)&Bis[sbr][sbk + 8] = bi1;

    __syncthreads();

#pragma unroll
    for (int kk = 0; kk < 2; ++kk) {
      const int ko = kk * 32 + (lane >> 4) * 8;
      bf16x8 afr = *(const bf16x8*)&Ars[wm * 16 + (lane & 15)][ko];
      bf16x8 afi = *(const bf16x8*)&Ais[wm * 16 + (lane & 15)][ko];
      i32x4 neg = (i32x4)afi ^ (int)0x80008000;
      bf16x8 afin = (bf16x8)neg;
#pragma unroll
      for (int nf = 0; nf < 2; ++nf) {
        bf16x8 bfr = *(const bf16x8*)&Brs[wn * 32 + nf * 16 + (lane & 15)][ko];
        bf16x8 bfi = *(const bf16x8*)&Bis[wn * 32 + nf * 16 + (lane & 15)][ko];
        acc_r[nf] = __builtin_amdgcn_mfma_f32_16x16x32_bf16(afr,  bfr, acc_r[nf], 0, 0, 0);
        acc_r[nf] = __builtin_amdgcn_mfma_f32_16x16x32_bf16(afin, bfi, acc_r[nf], 0, 0, 0);
        acc_i[nf] = __builtin_amdgcn_mfma_f32_16x16x32_bf16(afr,  bfi, acc_i[nf], 0, 0, 0);
        acc_i[nf] = __builtin_amdgcn_mfma_f32_16x16x32_bf16(afi,  bfr, acc_i[nf], 0, 0, 0);
      }
    }
  }

  const int dn0 = bn + wn * 32 + (lane & 15);
  const int dm0 = bm + wm * 16 + (lane >> 4) * 4;
#pragma unroll
  for (int nf = 0; nf < 2; ++nf) {
    const int n = dn0 + nf * 16;
#pragma unroll
    for (int r = 0; r < 4; ++r) {
      Or[(size_t)(dm0 + r) * NF + n] = f2bf(acc_r[nf][r]);
      Oi[(size_t)(dm0 + r) * NF + n] = f2bf(acc_i[nf][r]);
    }
  }
}

// ---------------- K3: U = C1 * C0 (N out): out[i][j] = sum_k C1[i][k] * C0T[j][k] ----------------
__global__ __launch_bounds__(256) void prodU_kernel(
    const unsigned short* __restrict__ Cb, unsigned short* __restrict__ Up)
{
  __shared__ __align__(16) unsigned short Ars[32][LDT];
  __shared__ __align__(16) unsigned short Ais[32][LDT];
  __shared__ __align__(16) unsigned short Brs[64][LDT];
  __shared__ __align__(16) unsigned short Bis[64][LDT];

  const int tid = threadIdx.x;
  const int t = blockIdx.x;                    // 0..127
  const int bm = (t >> 3) * 32, bn = (t & 7) * 64;
  const unsigned short* C0T = Cb;                      // C0 T-plane
  const unsigned short* C1N = Cb + (size_t)2 * PL;     // C1 N-plane
  const int hw = 70;                           // 32-step band 67 + margin
  int klo = bm - hw; { int u = bn - hw; if (u > klo) klo = u; }
  if (klo < 0) klo = 0; klo &= ~63;
  int khi = bm + 32 + hw; { int u = bn + 64 + hw; if (u < khi) khi = u; }
  if (khi > NF) khi = NF; khi = (khi + 63) & ~63;
  prod_tile(C1N, C1N + PL, C0T, C0T + PL, Up, Up + PL, bm, bn, klo, khi, tid,
            Ars, Ais, Brs, Bis);
}

// ---------------- K4: final banded GEMM — Y[r][n] = (sum_j X[r][j] U[n][j]) e^{i w_n} ----------------
__global__ __launch_bounds__(256) void gemm_kernel(
    const float2* __restrict__ Xf,
    const unsigned short* __restrict__ Ur, const unsigned short* __restrict__ Ui,
    const float* __restrict__ omega, float2* __restrict__ Y)
{
  __shared__ __align__(16) unsigned short Ars[32][LDT];
  __shared__ __align__(16) unsigned short Ais[32][LDT];
  __shared__ __align__(16) unsigned short Brs[64][LDT];
  __shared__ __align__(16) unsigned short Bis[64][LDT];

  const int tid = threadIdx.x;
  const int w = tid >> 6, wm = w & 1, wn = w >> 1;
  const int lane = tid & 63;
  const int bm = (blockIdx.x >> 3) * 32;
  const int bn = (blockIdx.x & 7) * 64;

  int klo = bn - 140; if (klo < 0) klo = 0; klo &= ~63;
  int khi = bn + 204; if (khi > NF) khi = NF; khi = (khi + 63) & ~63;

  f32x4 acc_r[2], acc_i[2];
#pragma unroll
  for (int nf = 0; nf < 2; ++nf) {
    acc_r[nf] = (f32x4){0.f, 0.f, 0.f, 0.f};
    acc_i[nf] = (f32x4){0.f, 0.f, 0.f, 0.f};
  }
  const int sar = tid >> 3, sak = (tid & 7) * 8;
  const int sbr = tid >> 2, sbk = (tid & 3) * 16;

  for (int k0 = klo; k0 < khi; k0 += 64) {
    ushort4 ar2[2], ai2[2];
    const float4* xs = (const float4*)(Xf + (size_t)(bm + sar) * NF + k0 + sak);
#pragma unroll
    for (int h = 0; h < 2; ++h) {
      float4 v0 = xs[2 * h], v1 = xs[2 * h + 1];
      ar2[h].x = f2bf(v0.x); ai2[h].x = f2bf(v0.y);
      ar2[h].y = f2bf(v0.z); ai2[h].y = f2bf(v0.w);
      ar2[h].z = f2bf(v1.x); ai2[h].z = f2bf(v1.y);
      ar2[h].w = f2bf(v1.z); ai2[h].w = f2bf(v1.w);
    }
    const uint4* gbr = (const uint4*)(Ur + (size_t)(bn + sbr) * NF + k0 + sbk);
    const uint4* gbi = (const uint4*)(Ui + (size_t)(bn + sbr) * NF + k0 + sbk);
    uint4 br0 = gbr[0], br1 = gbr[1];
    uint4 bi0 = gbi[0], bi1 = gbi[1];

    if (k0 > klo) __syncthreads();

    *(ushort4*)&Ars[sar][sak]     = ar2[0];
    *(ushort4*)&Ars[sar][sak + 4] = ar2[1];
    *(ushort4*)&Ais[sar][sak]     = ai2[0];
    *(ushort4*)&Ais[sar][sak + 4] = ai2[1];
    *(uint4*)&Brs[sbr][sbk]       = br0;
    *(uint4*)&Brs[sbr][sbk + 8]   = br1;
    *(uint4*)&Bis[sbr][sbk]       = bi0;
    *(uint4*)&Bis[sbr][sbk + 8]   = bi1;

    __syncthreads();

#pragma unroll
    for (int kk = 0; kk < 2; ++kk) {
      const int ko = kk * 32 + (lane >> 4) * 8;
      bf16x8 afr = *(const bf16x8*)&Ars[wm * 16 + (lane & 15)][ko];
      bf16x8 afi = *(const bf16x8*)&Ais[wm * 16 + (lane & 15)][ko];
      i32x4 neg = (i32x4)afi ^ (int)0x80008000;
      bf16x8 afin = (bf16x8)neg;
#pragma unroll
      for (int nf = 0; nf < 2; ++nf) {
        bf16x8 bfr = *(const bf16x8*)&Brs[wn * 32 + nf * 16 + (lane & 15)][ko];
        bf16x8 bfi = *(const bf16x8*)&Bis[wn * 32 + nf * 16 + (lane & 15)][ko];
        acc_r[nf] = __builtin_amdgcn_mfma_f32_16x16x32_bf16(afr,  bfr, acc_r[nf], 0, 0, 0);
        acc_r[nf] = __builtin_amdgcn_mfma_f32_16x16x32_bf16(afin, bfi, acc_r[nf], 0, 0, 0);
        acc_i[nf] = __builtin_amdgcn_mfma_f32_16x16x32_bf16(afr,  bfi, acc_i[nf], 0, 0, 0);
        acc_i[nf] = __builtin_amdgcn_mfma_f32_16x16x32_bf16(afi,  bfr, acc_i[nf], 0, 0, 0);
      }
    }
  }

  const int dn0 = bn + wn * 32 + (lane & 15);
  const int dm0 = bm + wm * 16 + (lane >> 4) * 4;
#pragma unroll
  for (int nf = 0; nf < 2; ++nf) {
    const int n = dn0 + nf * 16;
    float sn, cn;
    sincosf(omega[n], &sn, &cn);
#pragma unroll
    for (int r = 0; r < 4; ++r) {
      float yr = acc_r[nf][r], yi = acc_i[nf][r];
      Y[(size_t)(dm0 + r) * NF + n] =
          make_float2(fmaf(yr, cn, -(yi * sn)), fmaf(yr, sn, yi * cn));
    }
  }
}

extern "C" void kernel_launch(void* const* d_in, const int* in_sizes, int n_in,
                              void* d_out, int out_size, void* d_ws, size_t ws_size,
                              hipStream_t stream) {
  const float2* Xf   = (const float2*)d_in[0];  // (2048, 512) complex f32
  const float* a0    = (const float*)d_in[1];   // (64, 256)
  const float* a1    = (const float*)d_in[2];
  const float* b0    = (const float*)d_in[3];   // (64, 255)
  const float* b1    = (const float*)d_in[4];
  const float* omega = (const float*)d_in[5];

  size_t off = 0;
  unsigned short* Cb = (unsigned short*)((char*)d_ws + off); off += (size_t)2 * 2 * PL * 2;
  unsigned short* Up = (unsigned short*)((char*)d_ws + off); off += (size_t)1 * 2 * PL * 2;
  float2* Y = (float2*)d_out;

  chunk_mesh<<<1024, 64, 0, stream>>>(a0, a1, b0, b1, Cb);
  prodU_kernel<<<128, 256, 0, stream>>>(Cb, Up);
  gemm_kernel<<<(MB / 32) * (NF / 64), 256, 0, stream>>>(Xf, Up, Up + PL, omega, Y);
}